// Round 2
// baseline (765.002 us; speedup 1.0000x reference)
//
#include <hip/hip_runtime.h>
#include <math.h>

// GatingNetwork: logits = x[T,D]@W[D,E] + b; softmax; top-2.
// Output (fp32, flat): topk_w[T,2] | topk_idx[T,2] (as float) | weights[T,E].
//
// T=16384 D=2048 E=64. No fp32 MFMA on CDNA4 -> vector FMA.
// R2 design: grid 256 x 512 threads (8 waves/CU, 2/SIMD, fixes R1's 1-wave/SIMD
// latency bind). In-block 4-way K-split: slice s (128 threads) computes partial
// logits over d in [s*512, s*512+512), BK=32, register-prefetch, single LDS
// buffer (2 barriers/chunk). Micro-tile 8 tok x 4 exp per thread:
// 48 LDS-B/lane per 32 FMA-insts = 1.5 B/FMA -> 192 B/cyc/CU demand, under the
// 256 B/cyc LDS datapath. Epilogue: LDS tree-reduce 4 partials + bias, softmax,
// top-2 (strict > keeps lowest index, matching jax top_k).

#define T_TOK 16384
#define DMOD  2048
#define NEXP  64
#define TM    64
#define NSL   4
#define DSL   (DMOD / NSL)   // 512
#define BK    32
#define NCH   (DSL / BK)     // 16
#define NT    512

__global__ __launch_bounds__(NT) void gating_kernel(
    const float* __restrict__ x, const float* __restrict__ W,
    const float* __restrict__ bias, float* __restrict__ out) {
  // 64 KB exactly. K-loop: xs[4][32][64] floats at 0, ws[4][32][64] at 8192.
  // Epilogue overlays: lg[64][65] at 0, red_m at 4160, red_s at 4224.
  __shared__ float smem[16384];
  float* xs = smem;
  float* ws = smem + 8192;
  float* lg = smem;
  float* red_m = smem + 4160;
  float* red_s = smem + 4224;

  const int tid  = threadIdx.x;
  const int s    = tid >> 7;     // K-slice 0..3 (2 waves each; waves don't straddle)
  const int sl   = tid & 127;    // lane in slice
  const int tg   = sl >> 4;      // 0..7  -> tokens tg*8..+7
  const int eg   = sl & 15;      // 0..15 -> experts eg*4..+3
  const int tt   = sl >> 1;      // staging: token 0..63
  const int half = sl & 1;       // staging: which 16-float d-half
  const int t0   = blockIdx.x * TM;

  const float* xg = x + (size_t)(t0 + tt) * DMOD + s * DSL + half * 16;
  const float* wg = W + (size_t)(s * DSL) * NEXP;
  float* xs_s = xs + s * 2048;   // [d][t], d 0..31, t 0..63
  float* ws_s = ws + s * 2048;   // [d][e]

  float acc[8][4];
#pragma unroll
  for (int i = 0; i < 8; ++i)
#pragma unroll
    for (int e = 0; e < 4; ++e) acc[i][e] = 0.f;

  // ---- stage chunk 0 ----
  {
    float4 px[4], pw[4];
#pragma unroll
    for (int r = 0; r < 4; ++r) px[r] = *(const float4*)(xg + r * 4);
#pragma unroll
    for (int r = 0; r < 4; ++r) pw[r] = ((const float4*)wg)[r * 128 + sl];
#pragma unroll
    for (int r = 0; r < 4; ++r) {
      const int d = half * 16 + r * 4;
      xs_s[(d + 0) * 64 + tt] = px[r].x;
      xs_s[(d + 1) * 64 + tt] = px[r].y;
      xs_s[(d + 2) * 64 + tt] = px[r].z;
      xs_s[(d + 3) * 64 + tt] = px[r].w;
      ((float4*)ws_s)[r * 128 + sl] = pw[r];
    }
  }
  __syncthreads();

  for (int k = 0; k < NCH; ++k) {
    // register-prefetch chunk k+1 (2048 VALU-cyc of compute covers HBM latency)
    float4 px[4], pw[4];
    const bool nx = (k + 1 < NCH);
    if (nx) {
      const int kd = (k + 1) * BK;
#pragma unroll
      for (int r = 0; r < 4; ++r) px[r] = *(const float4*)(xg + kd + r * 4);
#pragma unroll
      for (int r = 0; r < 4; ++r)
        pw[r] = ((const float4*)(wg + (size_t)kd * NEXP))[r * 128 + sl];
    }
    // compute: 32 j x (3 ds_read_b128 + 32 FMA)
#pragma unroll
    for (int j = 0; j < BK; ++j) {
      const float4 xa = *(const float4*)(xs_s + j * 64 + tg * 8);
      const float4 xb = *(const float4*)(xs_s + j * 64 + tg * 8 + 4);
      const float4 wv = *(const float4*)(ws_s + j * 64 + eg * 4);
      acc[0][0] = fmaf(xa.x, wv.x, acc[0][0]);
      acc[0][1] = fmaf(xa.x, wv.y, acc[0][1]);
      acc[0][2] = fmaf(xa.x, wv.z, acc[0][2]);
      acc[0][3] = fmaf(xa.x, wv.w, acc[0][3]);
      acc[1][0] = fmaf(xa.y, wv.x, acc[1][0]);
      acc[1][1] = fmaf(xa.y, wv.y, acc[1][1]);
      acc[1][2] = fmaf(xa.y, wv.z, acc[1][2]);
      acc[1][3] = fmaf(xa.y, wv.w, acc[1][3]);
      acc[2][0] = fmaf(xa.z, wv.x, acc[2][0]);
      acc[2][1] = fmaf(xa.z, wv.y, acc[2][1]);
      acc[2][2] = fmaf(xa.z, wv.z, acc[2][2]);
      acc[2][3] = fmaf(xa.z, wv.w, acc[2][3]);
      acc[3][0] = fmaf(xa.w, wv.x, acc[3][0]);
      acc[3][1] = fmaf(xa.w, wv.y, acc[3][1]);
      acc[3][2] = fmaf(xa.w, wv.z, acc[3][2]);
      acc[3][3] = fmaf(xa.w, wv.w, acc[3][3]);
      acc[4][0] = fmaf(xb.x, wv.x, acc[4][0]);
      acc[4][1] = fmaf(xb.x, wv.y, acc[4][1]);
      acc[4][2] = fmaf(xb.x, wv.z, acc[4][2]);
      acc[4][3] = fmaf(xb.x, wv.w, acc[4][3]);
      acc[5][0] = fmaf(xb.y, wv.x, acc[5][0]);
      acc[5][1] = fmaf(xb.y, wv.y, acc[5][1]);
      acc[5][2] = fmaf(xb.y, wv.z, acc[5][2]);
      acc[5][3] = fmaf(xb.y, wv.w, acc[5][3]);
      acc[6][0] = fmaf(xb.z, wv.x, acc[6][0]);
      acc[6][1] = fmaf(xb.z, wv.y, acc[6][1]);
      acc[6][2] = fmaf(xb.z, wv.z, acc[6][2]);
      acc[6][3] = fmaf(xb.z, wv.w, acc[6][3]);
      acc[7][0] = fmaf(xb.w, wv.x, acc[7][0]);
      acc[7][1] = fmaf(xb.w, wv.y, acc[7][1]);
      acc[7][2] = fmaf(xb.w, wv.z, acc[7][2]);
      acc[7][3] = fmaf(xb.w, wv.w, acc[7][3]);
    }
    __syncthreads();  // all reads of this chunk done before overwrite
    if (nx) {
#pragma unroll
      for (int r = 0; r < 4; ++r) {
        const int d = half * 16 + r * 4;
        xs_s[(d + 0) * 64 + tt] = px[r].x;
        xs_s[(d + 1) * 64 + tt] = px[r].y;
        xs_s[(d + 2) * 64 + tt] = px[r].z;
        xs_s[(d + 3) * 64 + tt] = px[r].w;
        ((float4*)ws_s)[r * 128 + sl] = pw[r];
      }
    }
    __syncthreads();
  }

  // ---- reduce 4 K-slice partials into lg[64][65] (overlays xs; +bias) ----
  {
    const float4 bv = *(const float4*)(bias + eg * 4);
#pragma unroll
    for (int ss = 0; ss < NSL; ++ss) {
      if (s == ss) {
#pragma unroll
        for (int i = 0; i < 8; ++i) {
          float* lrow = lg + (tg * 8 + i) * 65 + eg * 4;
          if (ss == 0) {
            lrow[0] = acc[i][0] + bv.x;
            lrow[1] = acc[i][1] + bv.y;
            lrow[2] = acc[i][2] + bv.z;
            lrow[3] = acc[i][3] + bv.w;
          } else {
            lrow[0] += acc[i][0];
            lrow[1] += acc[i][1];
            lrow[2] += acc[i][2];
            lrow[3] += acc[i][3];
          }
        }
      }
      __syncthreads();
    }
  }

  // ---- softmax stats + top-2: one lane per token (wave 0) ----
  if (tid < TM) {
    float m = -INFINITY;
    for (int e = 0; e < NEXP; ++e) m = fmaxf(m, lg[tid * 65 + e]);
    float sum = 0.f, b1 = -INFINITY, b2 = -INFINITY;
    int i1 = 0, i2 = 0;
    for (int e = 0; e < NEXP; ++e) {
      const float v = lg[tid * 65 + e];
      sum += expf(v - m);
      if (v > b1) {          // strict >: ties keep lowest index (jax top_k order)
        b2 = b1; i2 = i1; b1 = v; i1 = e;
      } else if (v > b2) {
        b2 = v; i2 = e;
      }
    }
    const float inv = 1.f / sum;
    const int t = t0 + tid;
    out[2 * t + 0] = expf(b1 - m) * inv;
    out[2 * t + 1] = expf(b2 - m) * inv;
    out[2 * T_TOK + 2 * t + 0] = (float)i1;
    out[2 * T_TOK + 2 * t + 1] = (float)i2;
    red_m[tid] = m;
    red_s[tid] = inv;
  }
  __syncthreads();

  // ---- full softmax weights, coalesced ----
#pragma unroll
  for (int r = 0; r < (TM * NEXP) / NT; ++r) {
    const int idx = r * NT + tid;
    const int ttk = idx >> 6;
    const int e = idx & 63;
    out[4 * T_TOK + (size_t)(t0 + ttk) * NEXP + e] =
        expf(lg[ttk * 65 + e] - red_m[ttk]) * red_s[ttk];
  }
}

extern "C" void kernel_launch(void* const* d_in, const int* in_sizes, int n_in,
                              void* d_out, int out_size, void* d_ws, size_t ws_size,
                              hipStream_t stream) {
  const float* x = (const float*)d_in[0];
  const float* W = (const float*)d_in[1];
  const float* b = (const float*)d_in[2];
  float* out = (float*)d_out;
  gating_kernel<<<dim3(T_TOK / TM), dim3(NT), 0, stream>>>(x, W, b, out);
}

// Round 4
// 236.787 us; speedup vs baseline: 3.2308x; 3.2308x over previous
//
#include <hip/hip_runtime.h>
#include <math.h>

// GatingNetwork: logits = x[T,D]@W[D,E] + b; softmax; top-2.
// Output (fp32, flat): topk_w[T,2] | topk_idx[T,2] (as float) | weights[T,E].
//
// T=16384 D=2048 E=64. No fp32 MFMA on CDNA4 -> vector FMA.
// R4 = R2's proven-correct single-kernel structure (passed all harness
// tripwires incl. graph replay) minus the register spill:
//  - NO cross-phase register prefetch (R2 held 16 extra VGPRs live across the
//    whole compute phase -> spilled 1.65 GB scratch at the 128-reg cap).
//  - per chunk: stage -> barrier -> compute -> barrier. Latency hidden by
//    wave-level overlap: 512-thr blocks, 32 KB LDS -> 2 blocks/CU = 16
//    waves/CU = 4 waves/SIMD (m114: co-resident blocks overlap barriers).
//  - __launch_bounds__(512,4): VGPR cap 128; peak live ~75 -> no spill.
// In-block 4-way K-split: slice s (128 threads, 2 waves) computes partial
// logits over d in [s*512, (s+1)*512), BK=32. Micro-tile 8 tok x 4 exp:
// 48 LDS-B per 32 FMA = 1.5 B/FMA -> 192 B/cyc/CU < 256 B/cyc LDS datapath.
// Epilogue: LDS reduce 4 partials + bias, softmax, top-2 (strict > keeps
// lowest index, matching jax top_k). No d_ws, single launch.

#define T_TOK 16384
#define DMOD  2048
#define NEXP  64
#define TM    64
#define NSL   4
#define DSL   (DMOD / NSL)   // 512
#define BK    32
#define NCH   (DSL / BK)     // 16
#define NT    512

__global__ __launch_bounds__(NT, 4) void gating_kernel(
    const float* __restrict__ x, const float* __restrict__ W,
    const float* __restrict__ bias, float* __restrict__ out) {
  // 64 KB: xs[4][32][64] at 0 (x transposed [d][t] per slice), ws[4][32][64]
  // at 8192 ([d][e]). Epilogue overlays: lg[64][65] at 0, red_m/red_s after.
  __shared__ float smem[16384];
  float* xs = smem;
  float* wsm = smem + 8192;
  float* lg = smem;
  float* red_m = smem + 4160;
  float* red_s = smem + 4224;

  const int tid  = threadIdx.x;
  const int s    = tid >> 7;     // K-slice 0..3 (2 whole waves each)
  const int sl   = tid & 127;    // lane in slice
  const int tg   = sl >> 4;      // 0..7  -> tokens tg*8..+7
  const int eg   = sl & 15;      // 0..15 -> experts eg*4..+3
  const int tt   = sl >> 1;      // staging: token 0..63
  const int half = sl & 1;       // staging: which 16-float d-half
  const int t0   = blockIdx.x * TM;

  const float* xg = x + (size_t)(t0 + tt) * DMOD + s * DSL + half * 16;
  const float* wg = W + (size_t)(s * DSL) * NEXP;
  float* xs_s = xs + s * 2048;   // [d][t], d 0..31, t 0..63
  float* ws_s = wsm + s * 2048;  // [d][e]

  float acc[8][4];
#pragma unroll
  for (int i = 0; i < 8; ++i)
#pragma unroll
    for (int e = 0; e < 4; ++e) acc[i][e] = 0.f;

  for (int k = 0; k < NCH; ++k) {
    // ---- stage chunk k (transient registers only) ----
    {
      const int kd = k * BK;
      float4 px[4], pw[4];
#pragma unroll
      for (int r = 0; r < 4; ++r) px[r] = *(const float4*)(xg + kd + r * 4);
#pragma unroll
      for (int r = 0; r < 4; ++r)
        pw[r] = ((const float4*)(wg + (size_t)kd * NEXP))[r * 128 + sl];
#pragma unroll
      for (int r = 0; r < 4; ++r) {
        const int d = half * 16 + r * 4;
        xs_s[(d + 0) * 64 + tt] = px[r].x;
        xs_s[(d + 1) * 64 + tt] = px[r].y;
        xs_s[(d + 2) * 64 + tt] = px[r].z;
        xs_s[(d + 3) * 64 + tt] = px[r].w;
        ((float4*)ws_s)[r * 128 + sl] = pw[r];
      }
    }
    __syncthreads();
    // ---- compute: 32 j x (3 ds_read_b128 + 32 FMA) ----
#pragma unroll
    for (int j = 0; j < BK; ++j) {
      const float4 xa = *(const float4*)(xs_s + j * 64 + tg * 8);
      const float4 xb = *(const float4*)(xs_s + j * 64 + tg * 8 + 4);
      const float4 wv = *(const float4*)(ws_s + j * 64 + eg * 4);
      acc[0][0] = fmaf(xa.x, wv.x, acc[0][0]);
      acc[0][1] = fmaf(xa.x, wv.y, acc[0][1]);
      acc[0][2] = fmaf(xa.x, wv.z, acc[0][2]);
      acc[0][3] = fmaf(xa.x, wv.w, acc[0][3]);
      acc[1][0] = fmaf(xa.y, wv.x, acc[1][0]);
      acc[1][1] = fmaf(xa.y, wv.y, acc[1][1]);
      acc[1][2] = fmaf(xa.y, wv.z, acc[1][2]);
      acc[1][3] = fmaf(xa.y, wv.w, acc[1][3]);
      acc[2][0] = fmaf(xa.z, wv.x, acc[2][0]);
      acc[2][1] = fmaf(xa.z, wv.y, acc[2][1]);
      acc[2][2] = fmaf(xa.z, wv.z, acc[2][2]);
      acc[2][3] = fmaf(xa.z, wv.w, acc[2][3]);
      acc[3][0] = fmaf(xa.w, wv.x, acc[3][0]);
      acc[3][1] = fmaf(xa.w, wv.y, acc[3][1]);
      acc[3][2] = fmaf(xa.w, wv.z, acc[3][2]);
      acc[3][3] = fmaf(xa.w, wv.w, acc[3][3]);
      acc[4][0] = fmaf(xb.x, wv.x, acc[4][0]);
      acc[4][1] = fmaf(xb.x, wv.y, acc[4][1]);
      acc[4][2] = fmaf(xb.x, wv.z, acc[4][2]);
      acc[4][3] = fmaf(xb.x, wv.w, acc[4][3]);
      acc[5][0] = fmaf(xb.y, wv.x, acc[5][0]);
      acc[5][1] = fmaf(xb.y, wv.y, acc[5][1]);
      acc[5][2] = fmaf(xb.y, wv.z, acc[5][2]);
      acc[5][3] = fmaf(xb.y, wv.w, acc[5][3]);
      acc[6][0] = fmaf(xb.z, wv.x, acc[6][0]);
      acc[6][1] = fmaf(xb.z, wv.y, acc[6][1]);
      acc[6][2] = fmaf(xb.z, wv.z, acc[6][2]);
      acc[6][3] = fmaf(xb.z, wv.w, acc[6][3]);
      acc[7][0] = fmaf(xb.w, wv.x, acc[7][0]);
      acc[7][1] = fmaf(xb.w, wv.y, acc[7][1]);
      acc[7][2] = fmaf(xb.w, wv.z, acc[7][2]);
      acc[7][3] = fmaf(xb.w, wv.w, acc[7][3]);
    }
    __syncthreads();  // all reads of chunk k done before k+1 staging overwrites
  }

  // ---- reduce 4 K-slice partials into lg[64][65] (overlays xs; +bias) ----
  {
    const float4 bv = *(const float4*)(bias + eg * 4);
#pragma unroll
    for (int ss = 0; ss < NSL; ++ss) {
      if (s == ss) {
#pragma unroll
        for (int i = 0; i < 8; ++i) {
          float* lrow = lg + (tg * 8 + i) * 65 + eg * 4;
          if (ss == 0) {
            lrow[0] = acc[i][0] + bv.x;
            lrow[1] = acc[i][1] + bv.y;
            lrow[2] = acc[i][2] + bv.z;
            lrow[3] = acc[i][3] + bv.w;
          } else {
            lrow[0] += acc[i][0];
            lrow[1] += acc[i][1];
            lrow[2] += acc[i][2];
            lrow[3] += acc[i][3];
          }
        }
      }
      __syncthreads();
    }
  }

  // ---- softmax stats + top-2: one lane per token (wave 0) ----
  if (tid < TM) {
    float m = -INFINITY;
    for (int e = 0; e < NEXP; ++e) m = fmaxf(m, lg[tid * 65 + e]);
    float sum = 0.f, b1 = -INFINITY, b2 = -INFINITY;
    int i1 = 0, i2 = 0;
    for (int e = 0; e < NEXP; ++e) {
      const float v = lg[tid * 65 + e];
      sum += expf(v - m);
      if (v > b1) {          // strict >: ties keep lowest index (jax top_k)
        b2 = b1; i2 = i1; b1 = v; i1 = e;
      } else if (v > b2) {
        b2 = v; i2 = e;
      }
    }
    const float inv = 1.f / sum;
    const int t = t0 + tid;
    out[2 * t + 0] = expf(b1 - m) * inv;
    out[2 * t + 1] = expf(b2 - m) * inv;
    out[2 * T_TOK + 2 * t + 0] = (float)i1;
    out[2 * T_TOK + 2 * t + 1] = (float)i2;
    red_m[tid] = m;
    red_s[tid] = inv;
  }
  __syncthreads();

  // ---- full softmax weights, coalesced ----
#pragma unroll
  for (int r = 0; r < (TM * NEXP) / NT; ++r) {
    const int idx = r * NT + tid;
    const int ttk = idx >> 6;
    const int e = idx & 63;
    out[4 * T_TOK + (size_t)(t0 + ttk) * NEXP + e] =
        expf(lg[ttk * 65 + e] - red_m[ttk]) * red_s[ttk];
  }
}

extern "C" void kernel_launch(void* const* d_in, const int* in_sizes, int n_in,
                              void* d_out, int out_size, void* d_ws, size_t ws_size,
                              hipStream_t stream) {
  const float* x = (const float*)d_in[0];
  const float* W = (const float*)d_in[1];
  const float* b = (const float*)d_in[2];
  float* out = (float*)d_out;
  gating_kernel<<<dim3(T_TOK / TM), dim3(NT), 0, stream>>>(x, W, b, out);
}

// Round 6
// 227.632 us; speedup vs baseline: 3.3607x; 1.0402x over previous
//
#include <hip/hip_runtime.h>
#include <math.h>

// GatingNetwork: logits = x[T,D]@W[D,E] + b; softmax; top-2.
// Output (fp32, flat): topk_w[T,2] | topk_idx[T,2] (as float) | weights[T,E].
//
// R6: fp32 GEMM via EXACT 3-way bf16 split. x = h+m+l (3x8 mantissa bits
// covers fp32's 24), same for W; logits = hh + (hm+mh) + (mm+hl+lh), dropped
// terms ~2^-29 -> error at fp32-ordering noise level (R5's 3-term variant had
// ~1e-5 logit error and flipped a couple of near-tie top-2 indices).
// grid 256 x 512 thr, TM=64, BK=64, 32 chunks, register prefetch.
// LDS 54 KB: 6 bf16 planes [64][LDK=72] (xs h/m/l tokens-major, wt h/m/l
// experts-major, W transposed at staging). 2 blocks/CU = 16 waves/CU.
// MFMA 16x16x32_bf16; layouts (m89/m120): A[m=l&15][k=(l>>4)*8+j],
// B[k][n=l&15], D col=l&15 row=(l>>4)*4+r — validated by R5's passing
// topk-weights output. Wave w: m-tile w&3, n-pair w>>2. 12 MFMA/kstep.
// Epilogue: R5's proven softmax/top-2 (strict > keeps lowest index).

#define T_TOK 16384
#define DMOD  2048
#define NEXP  64
#define TM    64
#define BK    64
#define NCH   (DMOD / BK)   // 32
#define NT    512
#define LDK   72            // k-stride in shorts (144 B; frag ptrs 16-B aligned)

typedef __attribute__((ext_vector_type(8))) short short8;
typedef __attribute__((ext_vector_type(4))) float f32x4;

__device__ __forceinline__ unsigned short bf16_rne(float f) {
  unsigned int u = __float_as_uint(f);
  unsigned int r = (u + 0x7fffu + ((u >> 16) & 1u)) >> 16;
  return (unsigned short)r;
}
__device__ __forceinline__ float bf16_up(unsigned short h) {
  return __uint_as_float(((unsigned int)h) << 16);
}
__device__ __forceinline__ void split3(float v, unsigned short& h,
                                       unsigned short& m, unsigned short& l) {
  h = bf16_rne(v);
  const float e1 = v - bf16_up(h);
  m = bf16_rne(e1);
  const float e2 = e1 - bf16_up(m);
  l = bf16_rne(e2);
}

__global__ __launch_bounds__(NT, 4) void gating_kernel(
    const float* __restrict__ x, const float* __restrict__ W,
    const float* __restrict__ bias, float* __restrict__ out) {
  // 6 planes x 64 rows x 72 shorts = 55296 B. Epilogue overlays floats:
  // lg[64][65] at 0 (16640 B), red_m at float 4160, red_s at 4224.
  __shared__ __align__(16) unsigned short smem[6 * TM * LDK];
  unsigned short* xs_h = smem;
  unsigned short* xs_m = smem + TM * LDK;
  unsigned short* xs_l = smem + 2 * TM * LDK;
  unsigned short* wt_h = smem + 3 * TM * LDK;
  unsigned short* wt_m = smem + 4 * TM * LDK;
  unsigned short* wt_l = smem + 5 * TM * LDK;
  float* lg    = (float*)smem;
  float* red_m = (float*)smem + 4160;
  float* red_s = (float*)smem + 4224;

  const int tid = threadIdx.x;
  const int l   = tid & 63;
  const int w   = tid >> 6;
  const int q   = l >> 4;
  const int c   = l & 15;
  const int t0  = blockIdx.x * TM;

  // staging maps
  const int xtok = tid >> 3;          // 0..63
  const int xk0  = (tid & 7) * 8;     // 0..56
  const int wn0  = (tid & 31) * 2;    // 0..62
  const int wk0  = (tid >> 5) * 4;    // 0..60
  const float* xg = x + (size_t)(t0 + xtok) * DMOD + xk0;
  const float* wg = W + (size_t)wk0 * NEXP + wn0;

  // compute maps
  const int arow = (w & 3) * 16 + c;
  const int bn0  = (w >> 2) * 32 + c;
  const unsigned short* pa_h = xs_h + arow * LDK + q * 8;
  const unsigned short* pa_m = xs_m + arow * LDK + q * 8;
  const unsigned short* pa_l = xs_l + arow * LDK + q * 8;
  const unsigned short* pb_h = wt_h + bn0 * LDK + q * 8;
  const unsigned short* pb_m = wt_m + bn0 * LDK + q * 8;
  const unsigned short* pb_l = wt_l + bn0 * LDK + q * 8;

  f32x4 acc0 = {0.f, 0.f, 0.f, 0.f};
  f32x4 acc1 = {0.f, 0.f, 0.f, 0.f};

  float4 pxa, pxb;
  float2 pwv[4];
  // prologue: load chunk 0
  pxa = *(const float4*)(xg);
  pxb = *(const float4*)(xg + 4);
#pragma unroll
  for (int i = 0; i < 4; ++i) pwv[i] = *(const float2*)(wg + (size_t)i * NEXP);

  for (int k = 0; k < NCH; ++k) {
    // ---- convert + LDS write chunk k (from prefetch regs) ----
    {
      float xv[8] = {pxa.x, pxa.y, pxa.z, pxa.w, pxb.x, pxb.y, pxb.z, pxb.w};
      unsigned short h[8], m[8], lo[8];
#pragma unroll
      for (int j = 0; j < 8; ++j) split3(xv[j], h[j], m[j], lo[j]);
      uint4 hp, mp, lp;
      hp.x = (unsigned)h[0] | ((unsigned)h[1] << 16);
      hp.y = (unsigned)h[2] | ((unsigned)h[3] << 16);
      hp.z = (unsigned)h[4] | ((unsigned)h[5] << 16);
      hp.w = (unsigned)h[6] | ((unsigned)h[7] << 16);
      mp.x = (unsigned)m[0] | ((unsigned)m[1] << 16);
      mp.y = (unsigned)m[2] | ((unsigned)m[3] << 16);
      mp.z = (unsigned)m[4] | ((unsigned)m[5] << 16);
      mp.w = (unsigned)m[6] | ((unsigned)m[7] << 16);
      lp.x = (unsigned)lo[0] | ((unsigned)lo[1] << 16);
      lp.y = (unsigned)lo[2] | ((unsigned)lo[3] << 16);
      lp.z = (unsigned)lo[4] | ((unsigned)lo[5] << 16);
      lp.w = (unsigned)lo[6] | ((unsigned)lo[7] << 16);
      *(uint4*)(xs_h + xtok * LDK + xk0) = hp;
      *(uint4*)(xs_m + xtok * LDK + xk0) = mp;
      *(uint4*)(xs_l + xtok * LDK + xk0) = lp;
      // W: 4k x 2n regs -> transpose -> wt[n][k..k+3], b64 writes per plane
#pragma unroll
      for (int n = 0; n < 2; ++n) {
        unsigned short wh[4], wm[4], wl[4];
#pragma unroll
        for (int i = 0; i < 4; ++i) {
          const float v = n == 0 ? pwv[i].x : pwv[i].y;
          split3(v, wh[i], wm[i], wl[i]);
        }
        uint2 hp2, mp2, lp2;
        hp2.x = (unsigned)wh[0] | ((unsigned)wh[1] << 16);
        hp2.y = (unsigned)wh[2] | ((unsigned)wh[3] << 16);
        mp2.x = (unsigned)wm[0] | ((unsigned)wm[1] << 16);
        mp2.y = (unsigned)wm[2] | ((unsigned)wm[3] << 16);
        lp2.x = (unsigned)wl[0] | ((unsigned)wl[1] << 16);
        lp2.y = (unsigned)wl[2] | ((unsigned)wl[3] << 16);
        *(uint2*)(wt_h + (wn0 + n) * LDK + wk0) = hp2;
        *(uint2*)(wt_m + (wn0 + n) * LDK + wk0) = mp2;
        *(uint2*)(wt_l + (wn0 + n) * LDK + wk0) = lp2;
      }
    }
    __syncthreads();

    // ---- prefetch chunk k+1 (in flight during compute) ----
    if (k + 1 < NCH) {
      const int kc = (k + 1) * BK;
      pxa = *(const float4*)(xg + kc);
      pxb = *(const float4*)(xg + kc + 4);
#pragma unroll
      for (int i = 0; i < 4; ++i)
        pwv[i] = *(const float2*)(wg + (size_t)(kc + i) * NEXP);
    }

    // ---- compute chunk k: 2 ksteps x (9 b128 reads + 12 MFMA) ----
#pragma unroll
    for (int s = 0; s < 2; ++s) {
      const int ko = s * 32;
      const short8 a_h = *(const short8*)(pa_h + ko);
      const short8 a_m = *(const short8*)(pa_m + ko);
      const short8 a_l = *(const short8*)(pa_l + ko);
      const short8 b_h0 = *(const short8*)(pb_h + ko);
      const short8 b_m0 = *(const short8*)(pb_m + ko);
      const short8 b_l0 = *(const short8*)(pb_l + ko);
      const short8 b_h1 = *(const short8*)(pb_h + 16 * LDK + ko);
      const short8 b_m1 = *(const short8*)(pb_m + 16 * LDK + ko);
      const short8 b_l1 = *(const short8*)(pb_l + 16 * LDK + ko);
      acc0 = __builtin_amdgcn_mfma_f32_16x16x32_bf16(a_h, b_h0, acc0, 0, 0, 0);
      acc0 = __builtin_amdgcn_mfma_f32_16x16x32_bf16(a_h, b_m0, acc0, 0, 0, 0);
      acc0 = __builtin_amdgcn_mfma_f32_16x16x32_bf16(a_m, b_h0, acc0, 0, 0, 0);
      acc0 = __builtin_amdgcn_mfma_f32_16x16x32_bf16(a_m, b_m0, acc0, 0, 0, 0);
      acc0 = __builtin_amdgcn_mfma_f32_16x16x32_bf16(a_h, b_l0, acc0, 0, 0, 0);
      acc0 = __builtin_amdgcn_mfma_f32_16x16x32_bf16(a_l, b_h0, acc0, 0, 0, 0);
      acc1 = __builtin_amdgcn_mfma_f32_16x16x32_bf16(a_h, b_h1, acc1, 0, 0, 0);
      acc1 = __builtin_amdgcn_mfma_f32_16x16x32_bf16(a_h, b_m1, acc1, 0, 0, 0);
      acc1 = __builtin_amdgcn_mfma_f32_16x16x32_bf16(a_m, b_h1, acc1, 0, 0, 0);
      acc1 = __builtin_amdgcn_mfma_f32_16x16x32_bf16(a_m, b_m1, acc1, 0, 0, 0);
      acc1 = __builtin_amdgcn_mfma_f32_16x16x32_bf16(a_h, b_l1, acc1, 0, 0, 0);
      acc1 = __builtin_amdgcn_mfma_f32_16x16x32_bf16(a_l, b_h1, acc1, 0, 0, 0);
    }
    __syncthreads();  // reads of chunk k done before next write phase
  }

  // ---- logits -> lg[64][65] (D: col=l&15, row=(l>>4)*4+r) + bias ----
  {
    const int row0 = (w & 3) * 16 + q * 4;
    const int e0 = (w >> 2) * 32 + c;
    const float bv0 = bias[e0];
    const float bv1 = bias[e0 + 16];
#pragma unroll
    for (int r = 0; r < 4; ++r) {
      lg[(row0 + r) * 65 + e0] = acc0[r] + bv0;
      lg[(row0 + r) * 65 + e0 + 16] = acc1[r] + bv1;
    }
  }
  __syncthreads();

  // ---- softmax stats + top-2: one lane per token ----
  if (tid < TM) {
    float mx = -INFINITY;
    for (int e = 0; e < NEXP; ++e) mx = fmaxf(mx, lg[tid * 65 + e]);
    float sum = 0.f, b1 = -INFINITY, b2 = -INFINITY;
    int i1 = 0, i2 = 0;
    for (int e = 0; e < NEXP; ++e) {
      const float v = lg[tid * 65 + e];
      sum += expf(v - mx);
      if (v > b1) {          // strict >: ties keep lowest index (jax top_k)
        b2 = b1; i2 = i1; b1 = v; i1 = e;
      } else if (v > b2) {
        b2 = v; i2 = e;
      }
    }
    const float inv = 1.f / sum;
    const int t = t0 + tid;
    out[2 * t + 0] = expf(b1 - mx) * inv;
    out[2 * t + 1] = expf(b2 - mx) * inv;
    out[2 * T_TOK + 2 * t + 0] = (float)i1;
    out[2 * T_TOK + 2 * t + 1] = (float)i2;
    red_m[tid] = mx;
    red_s[tid] = inv;
  }
  __syncthreads();

  // ---- full softmax weights, coalesced ----
#pragma unroll
  for (int r = 0; r < (TM * NEXP) / NT; ++r) {
    const int idx = r * NT + tid;
    const int tt = idx >> 6;
    const int e = idx & 63;
    out[4 * T_TOK + (size_t)(t0 + tt) * NEXP + e] =
        expf(lg[tt * 65 + e] - red_m[tt]) * red_s[tt];
  }
}

extern "C" void kernel_launch(void* const* d_in, const int* in_sizes, int n_in,
                              void* d_out, int out_size, void* d_ws, size_t ws_size,
                              hipStream_t stream) {
  const float* x = (const float*)d_in[0];
  const float* W = (const float*)d_in[1];
  const float* b = (const float*)d_in[2];
  float* out = (float*)d_out;
  gating_kernel<<<dim3(T_TOK / TM), dim3(NT), 0, stream>>>(x, W, b, out);
}